// Round 1
// baseline (167.004 us; speedup 1.0000x reference)
//
#include <hip/hip_runtime.h>
#include <hip/hip_bf16.h>

#define NV 512
#define NF 64
#define SCR_STRIDE 72   // bf16 elems per scratch row (64 data + 8 pad) -> 144B rows

typedef __attribute__((ext_vector_type(8))) short bf16x8;
typedef __attribute__((ext_vector_type(4))) float f32x4;

__device__ __forceinline__ unsigned short f2bf(float x) {
    unsigned u = __float_as_uint(x);
    unsigned r = (u + 0x7fffu + ((u >> 16) & 1u)) >> 16;
    return (unsigned short)r;
}

__global__ void k_zero(unsigned int* mask) {
    mask[blockIdx.x * 256 + threadIdx.x] = 0u;
}

__global__ void k_edges(const int* __restrict__ ei, int E, unsigned int* __restrict__ mask) {
    int e = blockIdx.x * 256 + threadIdx.x;
    if (e < E) {
        int s = ei[e];       // src  (edge_index[0])
        int d = ei[E + e];   // dst  (edge_index[1])
        atomicOr(&mask[d * 16 + (s >> 5)], 1u << (s & 31));
    }
}

// one wave per v: build sorted neighbor list (dedup'd) + S[v,:] = sum_{j in N(v)} alpha[v*V+j,:]
__global__ void k_nbrS(const unsigned int* __restrict__ mask, const float* __restrict__ alpha,
                       int* __restrict__ cnt, int* __restrict__ nbr, float* __restrict__ S) {
    int v = blockIdx.x;
    int f = threadIdx.x;   // 64 threads
    float acc = 0.f;
    int c = 0;
    for (int wd = 0; wd < 16; ++wd) {
        unsigned int bits = mask[v * 16 + wd];
        while (bits) {
            int b = __ffs(bits) - 1;
            bits &= bits - 1;
            int j = wd * 32 + b;
            acc += alpha[((size_t)v * NV + j) * NF + f];
            if (f == 0 && c < 64) nbr[v * 64 + c] = j;
            ++c;
        }
    }
    S[v * NF + f] = acc;
    if (f == 0) cnt[v] = (c < 64 ? c : 64);
}

__global__ __launch_bounds__(512, 1) void k_main(
    const float* __restrict__ alpha, const float* __restrict__ w1, const float* __restrict__ b1,
    const float* __restrict__ w2, const float* __restrict__ b2, const float* __restrict__ eps_p,
    const int* __restrict__ cnt, const int* __restrict__ nbr, const float* __restrict__ S,
    float* __restrict__ out)
{
    extern __shared__ char smem[];
    float* Aw = (float*)smem;                                        // [512][64] f32 = 128KB
    unsigned short* scr = (unsigned short*)(smem + NV * NF * 4);     // [8 waves][16][SCR_STRIDE] bf16

    const int w    = blockIdx.x;
    const int t    = threadIdx.x;
    const int lane = t & 63;
    const int wid  = t >> 6;
    const int nlo  = lane & 15;
    const int g    = lane >> 4;
    const int kbase = g * 8;
    const float ceps = 1.0f + eps_p[0];

    // ---- load w1/w2 B-fragments + biases into registers (one-time) ----
    // B-frag phi: lane l, frag(ks,nt), elem e  <->  k = ks*32 + (l>>4)*8 + e, n = nt*16 + (l&15)
    bf16x8 w1f[2][4], w2f[2][4];
#pragma unroll
    for (int ks = 0; ks < 2; ++ks)
#pragma unroll
        for (int nt = 0; nt < 4; ++nt) {
            bf16x8 a, b;
#pragma unroll
            for (int e = 0; e < 8; ++e) {
                int k = ks * 32 + kbase + e;
                a[e] = (short)f2bf(w1[k * NF + nt * 16 + nlo]);
                b[e] = (short)f2bf(w2[k * NF + nt * 16 + nlo]);
            }
            w1f[ks][nt] = a;
            w2f[ks][nt] = b;
        }
    float b1v[4], b2v[4];
#pragma unroll
    for (int nt = 0; nt < 4; ++nt) {
        b1v[nt] = b1[nt * 16 + nlo];
        b2v[nt] = b2[nt * 16 + nlo];
    }

    // ---- stage Aw block: alpha[w*512 .. w*512+511][0..63] into LDS (coalesced float4) ----
    {
        const float* src = alpha + (size_t)w * (NV * NF);
#pragma unroll
        for (int i = 0; i < 16; ++i) {
            int chunk = i * 512 + t;                     // 16B units, 8192 total
            f32x4 val = *(const f32x4*)(src + chunk * 4);
            *(f32x4*)(smem + (size_t)chunk * 16) = val;
        }
    }
    __syncthreads();

    unsigned short* myscr = scr + wid * 16 * SCR_STRIDE;

    // each wave owns v in [wid*64, wid*64+64), batches of 16
    for (int bb = 0; bb < 4; ++bb) {
        int v0 = wid * 64 + bb * 16;

        // prefetch per-v operands (issue all loads up front)
        float sv[16], rv[16];
        int jr[16], cv[16];
#pragma unroll
        for (int vi = 0; vi < 16; ++vi) {
            int v = v0 + vi;
            sv[vi] = S[v * NF + lane];
            rv[vi] = alpha[((size_t)v * NV + w) * NF + lane];
            jr[vi] = nbr[v * 64 + lane];
            cv[vi] = cnt[v];
        }

        // pre rows: t = S[v] + (1+eps)*alpha[v*V+w] + sum_{j in N(v)} Aw[j]
#pragma unroll
        for (int vi = 0; vi < 16; ++vi) {
            float tv = sv[vi] + ceps * rv[vi];
            int c = cv[vi];
            for (int k = 0; k < c; ++k) {
                int j = __builtin_amdgcn_readlane(jr[vi], k);
                tv += Aw[j * NF + lane];
            }
            myscr[vi * SCR_STRIDE + lane] = f2bf(tv);
        }

        // ---- layer 1: [16 x 64] @ w1, MFMA ----
        bf16x8 a0 = *(const bf16x8*)(myscr + nlo * SCR_STRIDE + kbase);
        bf16x8 a1 = *(const bf16x8*)(myscr + nlo * SCR_STRIDE + 32 + kbase);
        f32x4 acc[4];
#pragma unroll
        for (int nt = 0; nt < 4; ++nt) {
            f32x4 z = {0.f, 0.f, 0.f, 0.f};
            z = __builtin_amdgcn_mfma_f32_16x16x32_bf16(a0, w1f[0][nt], z, 0, 0, 0);
            z = __builtin_amdgcn_mfma_f32_16x16x32_bf16(a1, w1f[1][nt], z, 0, 0, 0);
            acc[nt] = z;
        }

        // relu + b1 -> bf16 -> scratch (C/D layout: row=(l>>4)*4+r, col=nt*16+(l&15))
#pragma unroll
        for (int nt = 0; nt < 4; ++nt)
#pragma unroll
            for (int r = 0; r < 4; ++r) {
                float hv = acc[nt][r] + b1v[nt];
                hv = hv > 0.f ? hv : 0.f;
                int row = g * 4 + r;
                myscr[row * SCR_STRIDE + nt * 16 + nlo] = f2bf(hv);
            }

        // ---- layer 2 ----
        bf16x8 h0 = *(const bf16x8*)(myscr + nlo * SCR_STRIDE + kbase);
        bf16x8 h1 = *(const bf16x8*)(myscr + nlo * SCR_STRIDE + 32 + kbase);
#pragma unroll
        for (int nt = 0; nt < 4; ++nt) {
            f32x4 z = {0.f, 0.f, 0.f, 0.f};
            z = __builtin_amdgcn_mfma_f32_16x16x32_bf16(h0, w2f[0][nt], z, 0, 0, 0);
            z = __builtin_amdgcn_mfma_f32_16x16x32_bf16(h1, w2f[1][nt], z, 0, 0, 0);
#pragma unroll
            for (int r = 0; r < 4; ++r) {
                int vv = v0 + g * 4 + r;
                out[((size_t)vv * NV + w) * NF + nt * 16 + nlo] = z[r] + b2v[nt];
            }
        }
    }
}

extern "C" void kernel_launch(void* const* d_in, const int* in_sizes, int n_in,
                              void* d_out, int out_size, void* d_ws, size_t ws_size,
                              hipStream_t stream) {
    const float* alpha = (const float*)d_in[0];
    const int*   ei    = (const int*)d_in[1];
    const float* w1    = (const float*)d_in[2];
    const float* b1    = (const float*)d_in[3];
    const float* w2    = (const float*)d_in[4];
    const float* b2    = (const float*)d_in[5];
    const float* eps   = (const float*)d_in[6];
    float* out = (float*)d_out;
    int E = in_sizes[1] / 2;

    // ws layout (u32/f32 units): mask[8192] | cnt[512] | nbr[512*64] | S[512*64]
    unsigned int* mask = (unsigned int*)d_ws;
    int*   cnt = (int*)d_ws + 8192;
    int*   nbr = (int*)d_ws + 8192 + 512;
    float* S   = (float*)d_ws + 8192 + 512 + 512 * 64;

    k_zero <<<32, 256, 0, stream>>>(mask);
    k_edges<<<(E + 255) / 256, 256, 0, stream>>>(ei, E, mask);
    k_nbrS <<<NV, 64, 0, stream>>>(mask, alpha, cnt, nbr, S);

    const int smem_bytes = NV * NF * 4 + 8 * 16 * SCR_STRIDE * 2;   // 131072 + 18432 = 149504
    hipFuncSetAttribute(reinterpret_cast<const void*>(k_main),
                        hipFuncAttributeMaxDynamicSharedMemorySize, smem_bytes);
    k_main <<<NV, 512, smem_bytes, stream>>>(alpha, w1, b1, w2, b2, eps, cnt, nbr, S, out);
}

// Round 2
// 124.583 us; speedup vs baseline: 1.3405x; 1.3405x over previous
//
#include <hip/hip_runtime.h>
#include <hip/hip_bf16.h>

#define NV 512
#define NF 64
#define SCR_STRIDE 72   // bf16 elems per scratch row (64 data + 8 pad) -> 144B rows

typedef __attribute__((ext_vector_type(8))) short bf16x8;
typedef __attribute__((ext_vector_type(4))) float f32x4;

__device__ __forceinline__ unsigned short f2bf(float x) {
    unsigned u = __float_as_uint(x);
    unsigned r = (u + 0x7fffu + ((u >> 16) & 1u)) >> 16;
    return (unsigned short)r;
}

__global__ void k_zero(unsigned int* mask) {
    mask[blockIdx.x * 256 + threadIdx.x] = 0u;
}

__global__ void k_edges(const int* __restrict__ ei, int E, unsigned int* __restrict__ mask) {
    int e = blockIdx.x * 256 + threadIdx.x;
    if (e < E) {
        int s = ei[e];       // src  (edge_index[0])
        int d = ei[E + e];   // dst  (edge_index[1])
        atomicOr(&mask[d * 16 + (s >> 5)], 1u << (s & 31));
    }
}

// one wave per v: sorted dedup'd neighbor list (padded to multiple of 8 with
// zero-row index 512) + S[v,:] = sum_{j in N(v)} alpha[v*V+j,:]
__global__ void k_nbrS(const unsigned int* __restrict__ mask, const float* __restrict__ alpha,
                       int* __restrict__ cnt, int* __restrict__ nbr, float* __restrict__ S) {
    int v = blockIdx.x;
    int f = threadIdx.x;   // 64 threads
    float acc = 0.f;
    int c = 0;
    for (int wd = 0; wd < 16; ++wd) {
        unsigned int bits = mask[v * 16 + wd];
        while (bits) {
            int b = __ffs(bits) - 1;
            bits &= bits - 1;
            int j = wd * 32 + b;
            acc += alpha[((size_t)v * NV + j) * NF + f];
            if (f == 0 && c < 64) nbr[v * 64 + c] = j;
            ++c;
        }
    }
    S[v * NF + f] = acc;
    if (f == 0) {
        int cs = (c < 64 ? c : 64);
        int cp = (cs + 7) & ~7;          // padded count (multiple of 8, <=64)
        for (int k = cs; k < cp; ++k) nbr[v * 64 + k] = 512;   // zero row
        cnt[v] = cp;
    }
}

__global__ __launch_bounds__(512, 1) void k_main(
    const float* __restrict__ alpha, const float* __restrict__ w1, const float* __restrict__ b1,
    const float* __restrict__ w2, const float* __restrict__ b2, const float* __restrict__ eps_p,
    const int* __restrict__ cnt, const int* __restrict__ nbr, const float* __restrict__ S,
    float* __restrict__ out)
{
    extern __shared__ char smem[];
    float* Aw = (float*)smem;                                          // [513][64] f32 (row 512 = zeros)
    unsigned short* scr = (unsigned short*)(smem + 513 * NF * 4);      // [8 waves][16][SCR_STRIDE] bf16

    const int w    = blockIdx.x;
    const int t    = threadIdx.x;
    const int lane = t & 63;
    const int wid  = t >> 6;
    const int nlo  = lane & 15;
    const int g    = lane >> 4;
    const int kbase = g * 8;
    const float ceps = 1.0f + eps_p[0];

    // ---- load w1/w2 B-fragments + biases into registers (one-time) ----
    // B-frag phi: lane l, frag(ks,nt), elem e  <->  k = ks*32 + (l>>4)*8 + e, n = nt*16 + (l&15)
    bf16x8 w1f[2][4], w2f[2][4];
#pragma unroll
    for (int ks = 0; ks < 2; ++ks)
#pragma unroll
        for (int nt = 0; nt < 4; ++nt) {
            bf16x8 a, b;
#pragma unroll
            for (int e = 0; e < 8; ++e) {
                int k = ks * 32 + kbase + e;
                a[e] = (short)f2bf(w1[k * NF + nt * 16 + nlo]);
                b[e] = (short)f2bf(w2[k * NF + nt * 16 + nlo]);
            }
            w1f[ks][nt] = a;
            w2f[ks][nt] = b;
        }
    float b1v[4], b2v[4];
#pragma unroll
    for (int nt = 0; nt < 4; ++nt) {
        b1v[nt] = b1[nt * 16 + nlo];
        b2v[nt] = b2[nt * 16 + nlo];
    }

    // ---- stage Aw block async: alpha[w*512 ...][0..63] -> LDS, 16B/lane ----
    {
        const float* src = alpha + (size_t)w * (NV * NF);
        const int wbase = (t & ~63);      // lane0's chunk within this wave
#pragma unroll
        for (int i = 0; i < 16; ++i) {
            __builtin_amdgcn_global_load_lds(
                (const __attribute__((address_space(1))) void*)(src + (size_t)(i * 512 + t) * 4),
                (__attribute__((address_space(3))) void*)(smem + (size_t)(i * 512 + wbase) * 16),
                16, 0, 0);
        }
        if (t < 64) Aw[512 * NF + t] = 0.f;   // zero row for padded neighbor slots
    }
    __syncthreads();

    unsigned short* myscr = scr + wid * 16 * SCR_STRIDE;

    // preload batch 0 operands (residual rv is a scattered HBM read -> prefetch)
    float rvn[16]; int jrn[16];
#pragma unroll
    for (int vi = 0; vi < 16; ++vi) {
        int v = wid * 64 + vi;
        rvn[vi] = alpha[((size_t)v * NV + w) * NF + lane];
        jrn[vi] = nbr[v * 64 + lane];
    }

    // each wave owns v in [wid*64, wid*64+64), batches of 16
#pragma unroll
    for (int bb = 0; bb < 4; ++bb) {
        int v0 = wid * 64 + bb * 16;

        float rv[16]; int jr[16];
#pragma unroll
        for (int vi = 0; vi < 16; ++vi) { rv[vi] = rvn[vi]; jr[vi] = jrn[vi]; }

        if (bb < 3) {   // prefetch next batch
#pragma unroll
            for (int vi = 0; vi < 16; ++vi) {
                int v = v0 + 16 + vi;
                rvn[vi] = alpha[((size_t)v * NV + w) * NF + lane];
                jrn[vi] = nbr[v * 64 + lane];
            }
        }

        float sv[16]; int cv[16];
#pragma unroll
        for (int vi = 0; vi < 16; ++vi) {
            int v = v0 + vi;
            sv[vi] = S[v * NF + lane];
            cv[vi] = cnt[v];
        }

        // pre rows: t = S[v] + (1+eps)*alpha[v*V+w] + sum_{j in N(v)} Aw[j]
        // neighbor gather unrolled 8-wide (count padded to x8) -> 8 LDS reads in flight
#pragma unroll
        for (int vi = 0; vi < 16; ++vi) {
            float tv = sv[vi] + ceps * rv[vi];
            int c = __builtin_amdgcn_readfirstlane(cv[vi]);
            float t0 = 0.f, t1 = 0.f, t2 = 0.f, t3 = 0.f;
            float t4 = 0.f, t5 = 0.f, t6 = 0.f, t7 = 0.f;
            for (int k = 0; k < c; k += 8) {
                int j0 = __builtin_amdgcn_readlane(jr[vi], k + 0);
                int j1 = __builtin_amdgcn_readlane(jr[vi], k + 1);
                int j2 = __builtin_amdgcn_readlane(jr[vi], k + 2);
                int j3 = __builtin_amdgcn_readlane(jr[vi], k + 3);
                int j4 = __builtin_amdgcn_readlane(jr[vi], k + 4);
                int j5 = __builtin_amdgcn_readlane(jr[vi], k + 5);
                int j6 = __builtin_amdgcn_readlane(jr[vi], k + 6);
                int j7 = __builtin_amdgcn_readlane(jr[vi], k + 7);
                t0 += Aw[j0 * NF + lane];
                t1 += Aw[j1 * NF + lane];
                t2 += Aw[j2 * NF + lane];
                t3 += Aw[j3 * NF + lane];
                t4 += Aw[j4 * NF + lane];
                t5 += Aw[j5 * NF + lane];
                t6 += Aw[j6 * NF + lane];
                t7 += Aw[j7 * NF + lane];
            }
            tv += ((t0 + t1) + (t2 + t3)) + ((t4 + t5) + (t6 + t7));
            myscr[vi * SCR_STRIDE + lane] = f2bf(tv);
        }

        // ---- layer 1: [16 x 64] @ w1, MFMA ----
        bf16x8 a0 = *(const bf16x8*)(myscr + nlo * SCR_STRIDE + kbase);
        bf16x8 a1 = *(const bf16x8*)(myscr + nlo * SCR_STRIDE + 32 + kbase);
        f32x4 acc[4];
#pragma unroll
        for (int nt = 0; nt < 4; ++nt) {
            f32x4 z = {0.f, 0.f, 0.f, 0.f};
            z = __builtin_amdgcn_mfma_f32_16x16x32_bf16(a0, w1f[0][nt], z, 0, 0, 0);
            z = __builtin_amdgcn_mfma_f32_16x16x32_bf16(a1, w1f[1][nt], z, 0, 0, 0);
            acc[nt] = z;
        }

        // relu + b1 -> bf16 -> scratch (C/D layout: row=(l>>4)*4+r, col=nt*16+(l&15))
#pragma unroll
        for (int nt = 0; nt < 4; ++nt)
#pragma unroll
            for (int r = 0; r < 4; ++r) {
                float hv = acc[nt][r] + b1v[nt];
                hv = hv > 0.f ? hv : 0.f;
                int row = g * 4 + r;
                myscr[row * SCR_STRIDE + nt * 16 + nlo] = f2bf(hv);
            }

        // ---- layer 2 ----
        bf16x8 h0 = *(const bf16x8*)(myscr + nlo * SCR_STRIDE + kbase);
        bf16x8 h1 = *(const bf16x8*)(myscr + nlo * SCR_STRIDE + 32 + kbase);
#pragma unroll
        for (int nt = 0; nt < 4; ++nt) {
            f32x4 z = {0.f, 0.f, 0.f, 0.f};
            z = __builtin_amdgcn_mfma_f32_16x16x32_bf16(h0, w2f[0][nt], z, 0, 0, 0);
            z = __builtin_amdgcn_mfma_f32_16x16x32_bf16(h1, w2f[1][nt], z, 0, 0, 0);
#pragma unroll
            for (int r = 0; r < 4; ++r) {
                int vv = v0 + g * 4 + r;
                out[((size_t)vv * NV + w) * NF + nt * 16 + nlo] = z[r] + b2v[nt];
            }
        }
    }
}

extern "C" void kernel_launch(void* const* d_in, const int* in_sizes, int n_in,
                              void* d_out, int out_size, void* d_ws, size_t ws_size,
                              hipStream_t stream) {
    const float* alpha = (const float*)d_in[0];
    const int*   ei    = (const int*)d_in[1];
    const float* w1    = (const float*)d_in[2];
    const float* b1    = (const float*)d_in[3];
    const float* w2    = (const float*)d_in[4];
    const float* b2    = (const float*)d_in[5];
    const float* eps   = (const float*)d_in[6];
    float* out = (float*)d_out;
    int E = in_sizes[1] / 2;

    // ws layout (u32/f32 units): mask[8192] | cnt[512] | nbr[512*64] | S[512*64]
    unsigned int* mask = (unsigned int*)d_ws;
    int*   cnt = (int*)d_ws + 8192;
    int*   nbr = (int*)d_ws + 8192 + 512;
    float* S   = (float*)d_ws + 8192 + 512 + 512 * 64;

    k_zero <<<32, 256, 0, stream>>>(mask);
    k_edges<<<(E + 255) / 256, 256, 0, stream>>>(ei, E, mask);
    k_nbrS <<<NV, 64, 0, stream>>>(mask, alpha, cnt, nbr, S);

    const int smem_bytes = 513 * NF * 4 + 8 * 16 * SCR_STRIDE * 2;   // 131328 + 18432 = 149760
    hipFuncSetAttribute(reinterpret_cast<const void*>(k_main),
                        hipFuncAttributeMaxDynamicSharedMemorySize, smem_bytes);
    k_main <<<NV, 512, smem_bytes, stream>>>(alpha, w1, b1, w2, b2, eps, cnt, nbr, S, out);
}

// Round 3
// 68.263 us; speedup vs baseline: 2.4465x; 1.8250x over previous
//
#include <hip/hip_runtime.h>
#include <hip/hip_bf16.h>

#define NV 512
#define NF 64
#define SCR_STRIDE 72     // bf16 elems per scratch row (64 data + 8 pad) -> 144B rows
#define MASK_STRIDE 17    // u32 per mask row (16 + 1 pad) -> bank-conflict-free

typedef __attribute__((ext_vector_type(8))) short bf16x8;
typedef __attribute__((ext_vector_type(4))) float f32x4;

union BF8 { bf16x8 v; unsigned u[4]; };

__device__ __forceinline__ unsigned short f2bf(float x) {
    unsigned u = __float_as_uint(x);
    unsigned r = (u + 0x7fffu + ((u >> 16) & 1u)) >> 16;
    return (unsigned short)r;
}

__global__ void k_zero(unsigned int* mask) {
    mask[blockIdx.x * 256 + threadIdx.x] = 0u;
}

__global__ void k_edges(const int* __restrict__ ei, int E, unsigned int* __restrict__ mask) {
    int e = blockIdx.x * 256 + threadIdx.x;
    if (e < E) {
        int s = ei[e];       // src  (edge_index[0])
        int d = ei[E + e];   // dst  (edge_index[1])
        atomicOr(&mask[d * 16 + (s >> 5)], 1u << (s & 31));
    }
}

// one wave per v: S[v,:] = sum_{j in N(v)} alpha[v*V+j,:]  (dedup'd via bitmask)
__global__ void k_S(const unsigned int* __restrict__ mask, const float* __restrict__ alpha,
                    float* __restrict__ S) {
    int v = blockIdx.x;
    int f = threadIdx.x;   // 64 threads
    float acc = 0.f;
    for (int wd = 0; wd < 16; ++wd) {
        unsigned int bits = mask[v * 16 + wd];
        while (bits) {
            int b = __ffs(bits) - 1;
            bits &= bits - 1;
            int j = wd * 32 + b;
            acc += alpha[((size_t)v * NV + j) * NF + f];
        }
    }
    S[v * NF + f] = acc;
}

// LDS map (bytes):
//   [0,      65536)  AwT bf16 [64 f][512 j], byte(f,j) = f*1024 + j*2, XOR-swz ^((f&7)<<4)
//   [65536, 100352)  maskL u32 [512][MASK_STRIDE]
//   [100352,118784)  scr bf16 [8 waves][16][SCR_STRIDE]
#define AWT_OFF  0
#define MASK_OFF 65536
#define SCR_OFF  100352

__global__ __launch_bounds__(512, 1) void k_main(
    const float* __restrict__ alpha, const float* __restrict__ w1, const float* __restrict__ b1,
    const float* __restrict__ w2, const float* __restrict__ b2, const float* __restrict__ eps_p,
    const unsigned int* __restrict__ mask, const float* __restrict__ S,
    float* __restrict__ out)
{
    extern __shared__ char smem[];
    unsigned int* maskL = (unsigned int*)(smem + MASK_OFF);
    unsigned short* scr = (unsigned short*)(smem + SCR_OFF);

    const int w    = blockIdx.x;
    const int t    = threadIdx.x;
    const int lane = t & 63;
    const int wid  = t >> 6;
    const int nlo  = lane & 15;
    const int g    = lane >> 4;
    const int kbase = g * 8;
    const float ceps = 1.0f + eps_p[0];

    // ---- w1/w2 B-fragments + biases into registers (one-time) ----
    // phi: lane l, frag(ks,nt), elem e  <->  k = ks*32 + (l>>4)*8 + e, n = nt*16 + (l&15)
    bf16x8 w1f[2][4], w2f[2][4];
#pragma unroll
    for (int ks = 0; ks < 2; ++ks)
#pragma unroll
        for (int nt = 0; nt < 4; ++nt) {
            bf16x8 a, b;
#pragma unroll
            for (int e = 0; e < 8; ++e) {
                int k = ks * 32 + kbase + e;
                a[e] = (short)f2bf(w1[k * NF + nt * 16 + nlo]);
                b[e] = (short)f2bf(w2[k * NF + nt * 16 + nlo]);
            }
            w1f[ks][nt] = a;
            w2f[ks][nt] = b;
        }
    float b1v[4], b2v[4];
#pragma unroll
    for (int nt = 0; nt < 4; ++nt) {
        b1v[nt] = b1[nt * 16 + nlo];
        b2v[nt] = b2[nt * 16 + nlo];
    }

    // ---- stage AwT (bf16, transposed, swizzled): Aw[j][f] = alpha[w*512+j][f] ----
    {
        const float* src = alpha + (size_t)w * (NV * NF);
#pragma unroll
        for (int i = 0; i < 2; ++i) {
            int task = i * 512 + t;          // 1024 tasks: 64 j-blocks x 16 f-quads
            int jb = task >> 4;              // j block of 8 rows
            int fq = task & 15;              // f quad (4 cols)
            f32x4 rows[8];
#pragma unroll
            for (int r = 0; r < 8; ++r)
                rows[r] = *(const f32x4*)(src + (size_t)(jb * 8 + r) * NF + fq * 4);
#pragma unroll
            for (int c = 0; c < 4; ++c) {
                int f = fq * 4 + c;
                BF8 p;
#pragma unroll
                for (int h = 0; h < 4; ++h) {
                    unsigned lo = f2bf(rows[2 * h][c]);
                    unsigned hi = f2bf(rows[2 * h + 1][c]);
                    p.u[h] = lo | (hi << 16);
                }
                int byte = f * 1024 + jb * 16;
                *(bf16x8*)(smem + (byte ^ ((f & 7) << 4))) = p.v;
            }
        }
        // stage mask -> padded LDS rows
#pragma unroll
        for (int q = 0; q < 16; ++q) {
            int idx = q * 512 + t;
            maskL[(idx >> 4) * MASK_STRIDE + (idx & 15)] = mask[idx];
        }
    }
    __syncthreads();

    // ---- main GEMM: pre[v][f] = sum_j adj[v,j] * Aw[j][f], wave owns 64 v-rows ----
    const int mbase = wid * 64;
    f32x4 acc[4][4];
#pragma unroll
    for (int mi = 0; mi < 4; ++mi)
#pragma unroll
        for (int nt = 0; nt < 4; ++nt)
            acc[mi][nt] = (f32x4){0.f, 0.f, 0.f, 0.f};

    const unsigned swz = (unsigned)((nlo & 7) << 4);
    for (int kk = 0; kk < 16; ++kk) {
        bf16x8 bfr[4];
#pragma unroll
        for (int nt = 0; nt < 4; ++nt) {
            int f = nt * 16 + nlo;
            unsigned byte = (unsigned)(f * 1024 + kk * 64 + g * 16);
            bfr[nt] = *(const bf16x8*)(smem + (byte ^ swz));
        }
#pragma unroll
        for (int mi = 0; mi < 4; ++mi) {
            unsigned word = maskL[(mbase + mi * 16 + nlo) * MASK_STRIDE + kk];
            unsigned byteb = (word >> (g * 8)) & 0xFFu;
            BF8 a;
#pragma unroll
            for (int h = 0; h < 4; ++h) {
                unsigned b0 = (byteb >> (2 * h)) & 1u;
                unsigned b1 = (byteb >> (2 * h + 1)) & 1u;
                a.u[h] = (b0 ? 0x3F80u : 0u) | (b1 ? 0x3F800000u : 0u);
            }
#pragma unroll
            for (int nt = 0; nt < 4; ++nt)
                acc[mi][nt] = __builtin_amdgcn_mfma_f32_16x16x32_bf16(a.v, bfr[nt], acc[mi][nt], 0, 0, 0);
        }
    }

    // ---- epilogue per m-tile: +S +ceps*rv -> bf16 scratch -> MLP (MFMA) -> out ----
    unsigned short* myscr = scr + wid * 16 * SCR_STRIDE;
#pragma unroll
    for (int mi = 0; mi < 4; ++mi) {
        int v0 = mbase + mi * 16;
#pragma unroll
        for (int nt = 0; nt < 4; ++nt) {
            int f = nt * 16 + nlo;
#pragma unroll
            for (int r = 0; r < 4; ++r) {
                int v = v0 + g * 4 + r;
                float pre = acc[mi][nt][r] + S[v * NF + f]
                          + ceps * alpha[((size_t)v * NV + w) * NF + f];
                myscr[(g * 4 + r) * SCR_STRIDE + f] = f2bf(pre);
            }
        }

        // layer 1
        bf16x8 a0 = *(const bf16x8*)(myscr + nlo * SCR_STRIDE + kbase);
        bf16x8 a1 = *(const bf16x8*)(myscr + nlo * SCR_STRIDE + 32 + kbase);
        f32x4 accm[4];
#pragma unroll
        for (int nt = 0; nt < 4; ++nt) {
            f32x4 z = {0.f, 0.f, 0.f, 0.f};
            z = __builtin_amdgcn_mfma_f32_16x16x32_bf16(a0, w1f[0][nt], z, 0, 0, 0);
            z = __builtin_amdgcn_mfma_f32_16x16x32_bf16(a1, w1f[1][nt], z, 0, 0, 0);
            accm[nt] = z;
        }

        // relu + b1 -> bf16 scratch (C/D: row=(l>>4)*4+r, col=nt*16+(l&15))
#pragma unroll
        for (int nt = 0; nt < 4; ++nt)
#pragma unroll
            for (int r = 0; r < 4; ++r) {
                float hv = accm[nt][r] + b1v[nt];
                hv = hv > 0.f ? hv : 0.f;
                myscr[(g * 4 + r) * SCR_STRIDE + nt * 16 + nlo] = f2bf(hv);
            }

        // layer 2
        bf16x8 h0 = *(const bf16x8*)(myscr + nlo * SCR_STRIDE + kbase);
        bf16x8 h1 = *(const bf16x8*)(myscr + nlo * SCR_STRIDE + 32 + kbase);
#pragma unroll
        for (int nt = 0; nt < 4; ++nt) {
            f32x4 z = {0.f, 0.f, 0.f, 0.f};
            z = __builtin_amdgcn_mfma_f32_16x16x32_bf16(h0, w2f[0][nt], z, 0, 0, 0);
            z = __builtin_amdgcn_mfma_f32_16x16x32_bf16(h1, w2f[1][nt], z, 0, 0, 0);
#pragma unroll
            for (int r = 0; r < 4; ++r) {
                int vv = v0 + g * 4 + r;
                out[((size_t)vv * NV + w) * NF + nt * 16 + nlo] = z[r] + b2v[nt];
            }
        }
    }
}

extern "C" void kernel_launch(void* const* d_in, const int* in_sizes, int n_in,
                              void* d_out, int out_size, void* d_ws, size_t ws_size,
                              hipStream_t stream) {
    const float* alpha = (const float*)d_in[0];
    const int*   ei    = (const int*)d_in[1];
    const float* w1    = (const float*)d_in[2];
    const float* b1    = (const float*)d_in[3];
    const float* w2    = (const float*)d_in[4];
    const float* b2    = (const float*)d_in[5];
    const float* eps   = (const float*)d_in[6];
    float* out = (float*)d_out;
    int E = in_sizes[1] / 2;

    // ws layout (u32/f32 units): mask[8192] | S[512*64]
    unsigned int* mask = (unsigned int*)d_ws;
    float* S = (float*)d_ws + 8192;

    k_zero <<<32, 256, 0, stream>>>(mask);
    k_edges<<<(E + 255) / 256, 256, 0, stream>>>(ei, E, mask);
    k_S    <<<NV, 64, 0, stream>>>(mask, alpha, S);

    const int smem_bytes = 118784;   // 64K AwT + 34816 maskL + 18432 scr
    hipFuncSetAttribute(reinterpret_cast<const void*>(k_main),
                        hipFuncAttributeMaxDynamicSharedMemorySize, smem_bytes);
    k_main <<<NV, 512, smem_bytes, stream>>>(alpha, w1, b1, w2, b2, eps, mask, S, out);
}